// Round 5
// baseline (250.242 us; speedup 1.0000x reference)
//
#include <hip/hip_runtime.h>
#include <math.h>

#define N_ 32
#define D_ 512
#define S_ 1600
#define K_ 64

typedef __attribute__((ext_vector_type(8))) short short8;   // 8 bf16 = 16 B (A/B frag)
typedef __attribute__((ext_vector_type(4))) float f32x4;    // acc frag

// float -> bf16 (round to nearest even), bit pattern in short
static __device__ __forceinline__ short f2bf(float f) {
    unsigned u = __float_as_uint(f);
    u += 0x7fffu + ((u >> 16) & 1u);
    return (short)(u >> 16);
}

// ---------------------------------------------------------------------------
// kW: conv_weight [64][512] fp32 -> bf16
// ---------------------------------------------------------------------------
__global__ __launch_bounds__(256) void kW(const float* __restrict__ w,
                                          short* __restrict__ w16)
{
    int i4 = (blockIdx.x * 256 + threadIdx.x) * 4;
    float4 v = *(const float4*)&w[i4];
    short4 h = {f2bf(v.x), f2bf(v.y), f2bf(v.z), f2bf(v.w)};
    *(short4*)&w16[i4] = h;
}

// ---------------------------------------------------------------------------
// kX: one pass over x producing
//   x16 [n][d][s]  bf16 (straight convert, for kB)
//   xT16[n][s][d]  bf16 (transpose via fp32 LDS tile, for kA)
//   ssqp[n][dt][s] fp32 partial sum of x^2 over each 64-d tile (for kA's inv)
// grid: n(32) x dt(8) x st(25) = 6400 blocks x 256 thr; tile = 64d x 64s.
// LDS tile pitch 65 floats: write banks 2-way, read banks 2-way (both free).
// ---------------------------------------------------------------------------
__global__ __launch_bounds__(256) void kX(const float* __restrict__ x,
                                          short* __restrict__ x16,
                                          short* __restrict__ xT16,
                                          float* __restrict__ ssqp)
{
    __shared__ float tile[64 * 65];
    const int bid = blockIdx.x;
    const int n  = bid / 200;
    const int dt = (bid % 200) / 25;
    const int st = bid % 25;
    const int d0 = dt * 64, s0 = st * 64;

    const int lk = threadIdx.x & 15;     // s-quad group
    const int dg = threadIdx.x >> 4;     // d-row group 0..15
    const int sg = lk * 4;

    const float* xb = x + ((size_t)n * D_ + d0) * S_ + s0;
    short* x16b = x16 + ((size_t)n * D_ + d0) * S_ + s0;

#pragma unroll
    for (int j = 0; j < 4; ++j) {
        int row = dg + 16 * j;
        float4 v = *(const float4*)&xb[(size_t)row * S_ + sg];
        short4 h = {f2bf(v.x), f2bf(v.y), f2bf(v.z), f2bf(v.w)};
        *(short4*)&x16b[(size_t)row * S_ + sg] = h;
        tile[row * 65 + sg + 0] = v.x;
        tile[row * 65 + sg + 1] = v.y;
        tile[row * 65 + sg + 2] = v.z;
        tile[row * 65 + sg + 3] = v.w;
    }
    __syncthreads();

    const int srow = threadIdx.x >> 2;          // 0..63 (s within tile)
    const int dseg = (threadIdx.x & 3) * 16;    // 0,16,32,48
    float ss = 0.f;
    short8 o0, o1;
#pragma unroll
    for (int u = 0; u < 8; ++u) {
        float v = tile[(dseg + u) * 65 + srow];
        ss += v * v;
        o0[u] = f2bf(v);
    }
#pragma unroll
    for (int u = 0; u < 8; ++u) {
        float v = tile[(dseg + 8 + u) * 65 + srow];
        ss += v * v;
        o1[u] = f2bf(v);
    }
    short* op = xT16 + ((size_t)n * S_ + s0 + srow) * D_ + d0 + dseg;
    *(short8*)op = o0;
    *(short8*)(op + 8) = o1;

    ss += __shfl_xor(ss, 1);
    ss += __shfl_xor(ss, 2);
    if ((threadIdx.x & 3) == 0)
        ssqp[((size_t)n * 8 + dt) * S_ + s0 + srow] = ss;
}

// ---------------------------------------------------------------------------
// kA: LDS-free MFMA GEMM logits[k][s] = sum_d w16[k][d] xT16[s][d], fused
// fp32 softmax over k (scaled by inv = 1/||x_s||, from ssqp).
//   aprime[n][k][s] = softmax * inv   (bf16)
//   asum[n][k]     += softmax          (fp32 atomics)
// grid: N*25 = 800 blocks x 256 thr; wave wv owns s = s0 + wv*16 + lk (16 s),
// all 64 k via kt. D[row=4q+r <- k (A op)][col=lk <- s (B op)] (round-4 verified).
// ---------------------------------------------------------------------------
__global__ __launch_bounds__(256) void kA(const short* __restrict__ w16,
                                          const short* __restrict__ xT16,
                                          const float* __restrict__ ssqp,
                                          short* __restrict__ aprime,
                                          float* __restrict__ asum)
{
    const int n  = blockIdx.x / 25;
    const int s0 = (blockIdx.x % 25) * 64;
    const int wv = threadIdx.x >> 6;
    const int l  = threadIdx.x & 63;
    const int lk = l & 15;
    const int q  = l >> 4;
    const int s  = s0 + wv * 16 + lk;

    const short* xr = xT16 + ((size_t)n * S_ + s) * D_;

    f32x4 acc[4];
#pragma unroll
    for (int kt = 0; kt < 4; ++kt) acc[kt] = (f32x4){0.f, 0.f, 0.f, 0.f};

#pragma unroll
    for (int dc = 0; dc < D_; dc += 32) {
        short8 bf = *(const short8*)&xr[dc + q * 8];
#pragma unroll
        for (int kt = 0; kt < 4; ++kt) {
            short8 af = *(const short8*)&w16[(kt * 16 + lk) * D_ + dc + q * 8];
            acc[kt] = __builtin_amdgcn_mfma_f32_16x16x32_bf16(af, bf, acc[kt], 0, 0, 0);
        }
    }

    // inv from ssq partials (8 d-tiles)
    float ssv = 0.f;
#pragma unroll
    for (int dt = 0; dt < 8; ++dt) ssv += ssqp[((size_t)n * 8 + dt) * S_ + s];
    const float inv = 1.0f / fmaxf(sqrtf(ssv), 1e-12f);

    // scaled logits; softmax over k = (kt,4q+r): in-lane 16 + cross-quad shfl
    float lg[4][4];
#pragma unroll
    for (int kt = 0; kt < 4; ++kt)
#pragma unroll
        for (int r = 0; r < 4; ++r) lg[kt][r] = acc[kt][r] * inv;

    float m = -1e30f;
#pragma unroll
    for (int kt = 0; kt < 4; ++kt)
#pragma unroll
        for (int r = 0; r < 4; ++r) m = fmaxf(m, lg[kt][r]);
    m = fmaxf(m, __shfl_xor(m, 16));
    m = fmaxf(m, __shfl_xor(m, 32));

    float e[4][4];
    float sum = 0.f;
#pragma unroll
    for (int kt = 0; kt < 4; ++kt)
#pragma unroll
        for (int r = 0; r < 4; ++r) {
            e[kt][r] = __expf(lg[kt][r] - m);
            sum += e[kt][r];
        }
    sum += __shfl_xor(sum, 16);
    sum += __shfl_xor(sum, 32);
    const float rs = 1.0f / sum;

    short* apb = aprime + (size_t)n * K_ * S_;
#pragma unroll
    for (int kt = 0; kt < 4; ++kt)
#pragma unroll
        for (int r = 0; r < 4; ++r) {
            const int k = kt * 16 + 4 * q + r;
            float p = e[kt][r] * rs;
            apb[(size_t)k * S_ + s] = f2bf(p * inv);
            float t = p;
            t += __shfl_xor(t, 1);
            t += __shfl_xor(t, 2);
            t += __shfl_xor(t, 4);
            t += __shfl_xor(t, 8);
            if (lk == 0) atomicAdd(&asum[n * K_ + k], t);
        }
}

// ---------------------------------------------------------------------------
// kB: LDS-free MFMA GEMM. agg[k][d] partial over s-split:
//   agg[k][d] = sum_s aprime[k][s] * x16[d][s]   (both s-contiguous bf16)
// grid: n(32) x dtile(4 of 128) x split(5 of 320s) = 640 blocks x 256 thr.
// ---------------------------------------------------------------------------
__global__ __launch_bounds__(256) void kB(const short* __restrict__ x16,
                                          const short* __restrict__ aprime,
                                          float* __restrict__ aggp)
{
    const int bid = blockIdx.x;
    const int n  = bid / 20;
    const int dt = (bid % 20) / 5;
    const int sp = bid % 5;
    const int wv = threadIdx.x >> 6;
    const int l  = threadIdx.x & 63;
    const int lk = l & 15;
    const int q  = l >> 4;
    const int dbase = dt * 128 + wv * 32;

    const short* ap = aprime + (size_t)n * K_ * S_;
    const short* xb = x16 + (size_t)n * D_ * S_;

    f32x4 acc[4][2];
#pragma unroll
    for (int kt = 0; kt < 4; ++kt)
#pragma unroll
        for (int ds = 0; ds < 2; ++ds) acc[kt][ds] = (f32x4){0.f, 0.f, 0.f, 0.f};

    for (int kst = 0; kst < 10; ++kst) {
        const int s = sp * 320 + kst * 32 + q * 8;
        short8 af[4];
#pragma unroll
        for (int kt = 0; kt < 4; ++kt)
            af[kt] = *(const short8*)&ap[(size_t)(kt * 16 + lk) * S_ + s];
        short8 bf[2];
#pragma unroll
        for (int ds = 0; ds < 2; ++ds)
            bf[ds] = *(const short8*)&xb[(size_t)(dbase + ds * 16 + lk) * S_ + s];
#pragma unroll
        for (int kt = 0; kt < 4; ++kt)
#pragma unroll
            for (int ds = 0; ds < 2; ++ds)
                acc[kt][ds] = __builtin_amdgcn_mfma_f32_16x16x32_bf16(af[kt], bf[ds], acc[kt][ds], 0, 0, 0);
    }

    float* ab = aggp + ((size_t)sp * N_ + n) * K_ * D_;
#pragma unroll
    for (int kt = 0; kt < 4; ++kt)
#pragma unroll
        for (int ds = 0; ds < 2; ++ds)
#pragma unroll
            for (int r = 0; r < 4; ++r)
                ab[(size_t)(kt * 16 + 4 * q + r) * D_ + dbase + ds * 16 + lk] = acc[kt][ds][r];
}

// ---------------------------------------------------------------------------
// kC: vlad = (sum of 5 agg partials) - asum*centroid; intra-L2-norm over d;
// global norm = /sqrt(K) = /8 exactly. grid: 2048 blocks x 256 thr.
// ---------------------------------------------------------------------------
__global__ __launch_bounds__(256) void kC(const float* __restrict__ aggp,
                                          const float* __restrict__ asum,
                                          const float* __restrict__ cent,
                                          float* __restrict__ out)
{
    __shared__ float red[4];
    const int tid = threadIdx.x;
    const int nk = blockIdx.x;
    const int k = nk & 63;
    const float as = asum[nk];
    const float* cb = cent + (size_t)k * D_;

    float v0 = 0.f, v1 = 0.f;
#pragma unroll
    for (int p = 0; p < 5; ++p) {
        const float* ag = aggp + (size_t)p * N_ * K_ * D_ + (size_t)nk * D_;
        v0 += ag[tid];
        v1 += ag[tid + 256];
    }
    v0 -= as * cb[tid];
    v1 -= as * cb[tid + 256];
    float ssq = v0 * v0 + v1 * v1;

    ssq += __shfl_xor(ssq, 32);
    ssq += __shfl_xor(ssq, 16);
    ssq += __shfl_xor(ssq, 8);
    ssq += __shfl_xor(ssq, 4);
    ssq += __shfl_xor(ssq, 2);
    ssq += __shfl_xor(ssq, 1);
    if ((tid & 63) == 0) red[tid >> 6] = ssq;
    __syncthreads();
    const float total = red[0] + red[1] + red[2] + red[3];
    const float scale = 1.0f / (fmaxf(sqrtf(total), 1e-12f) * 8.0f);

    out[(size_t)nk * D_ + tid]       = v0 * scale;
    out[(size_t)nk * D_ + tid + 256] = v1 * scale;
}

// ---------------------------------------------------------------------------
extern "C" void kernel_launch(void* const* d_in, const int* in_sizes, int n_in,
                              void* d_out, int out_size, void* d_ws, size_t ws_size,
                              hipStream_t stream)
{
    const float* x    = (const float*)d_in[0];   // [32,512,40,40]
    const float* w    = (const float*)d_in[1];   // [64,512]
    const float* cent = (const float*)d_in[2];   // [64,512]
    float* out = (float*)d_out;                  // [32, 32768]

    // ws carve (~134 MB), fp32 first, all 16B-aligned
    float* aggp   = (float*)d_ws;                          // 5*N*K*D
    float* asum   = aggp + (size_t)5 * N_ * K_ * D_;       // N*K
    float* ssqp   = asum + (size_t)N_ * K_;                // N*8*S
    short* aprime = (short*)(ssqp + (size_t)N_ * 8 * S_);  // N*K*S bf16
    short* w16    = aprime + (size_t)N_ * K_ * S_;         // K*D bf16
    short* x16    = w16 + (size_t)K_ * D_;                 // N*D*S bf16
    short* xT16   = x16 + (size_t)N_ * D_ * S_;            // N*S*D bf16

    hipMemsetAsync(asum, 0, (size_t)N_ * K_ * sizeof(float), stream);

    kW<<<32, 256, 0, stream>>>(w, w16);
    kX<<<N_ * 8 * 25, 256, 0, stream>>>(x, x16, xT16, ssqp);
    kA<<<N_ * (S_ / 64), 256, 0, stream>>>(w16, xT16, ssqp, aprime, asum);
    kB<<<N_ * 4 * 5, 256, 0, stream>>>(x16, aprime, aggp);
    kC<<<N_ * K_, 256, 0, stream>>>(aggp, asum, cent, out);
}

// Round 6
// 207.783 us; speedup vs baseline: 1.2043x; 1.2043x over previous
//
#include <hip/hip_runtime.h>
#include <math.h>

#define N_ 32
#define D_ 512
#define S_ 1600
#define K_ 64

typedef __attribute__((ext_vector_type(8))) short short8;   // 8 bf16 = 16 B (A/B frag)
typedef __attribute__((ext_vector_type(4))) float f32x4;    // acc frag

// float -> bf16 (round to nearest even), bit pattern in short
static __device__ __forceinline__ short f2bf(float f) {
    unsigned u = __float_as_uint(f);
    u += 0x7fffu + ((u >> 16) & 1u);
    return (short)(u >> 16);
}

// ---------------------------------------------------------------------------
// kW: conv_weight [64][512] fp32 -> bf16
// ---------------------------------------------------------------------------
__global__ __launch_bounds__(256) void kW(const float* __restrict__ w,
                                          short* __restrict__ w16)
{
    int i4 = (blockIdx.x * 256 + threadIdx.x) * 4;
    float4 v = *(const float4*)&w[i4];
    short4 h = {f2bf(v.x), f2bf(v.y), f2bf(v.z), f2bf(v.w)};
    *(short4*)&w16[i4] = h;
}

// ---------------------------------------------------------------------------
// kA: MFMA GEMM logits[k][s] = sum_d w16[k][d] * xbf[d][s] + fused softmax.
// x staged per 64-d chunk into LDS *transposed* T[s][d] (bf16, pitch 68
// shorts): thread = one s-column (lane-stride-1), loads d-row pairs as b32,
// packs 2xbf16, b32 LDS writes (4-way banks = cheap). Also emits x16[d][s]
// bf16 to global (coalesced) for kB. ssq accumulated per-thread in fp32.
//   aprime[n][k][s] = softmax_k * inv, bf16;  asum[n][k] += softmax (atomic)
// grid: N*25 = 800 blocks x 256 thr (4 waves). wave wv: k in [16wv,16wv+16),
// all 64 s. D[row=4q+r <- k (A op)][col=lk <- s (B op)]  (round-4 verified).
// ---------------------------------------------------------------------------
__global__ __launch_bounds__(256) void kA(const float* __restrict__ x,
                                          const short* __restrict__ w16,
                                          short* __restrict__ x16,
                                          short* __restrict__ aprime,
                                          float* __restrict__ asum)
{
    __shared__ short T[64 * 68];        // [s][d] pitch 68 shorts (136B rows, 8B-aligned)
    __shared__ float pssq[4][64];
    __shared__ float invL[64];
    __shared__ float wred[2][4][64];

    const int tid = threadIdx.x;
    const int n  = blockIdx.x / 25;
    const int s0 = (blockIdx.x % 25) * 64;
    const int wv = tid >> 6;
    const int l  = tid & 63;
    const int lk = l & 15;
    const int q  = l >> 4;

    const float* xb = x + (size_t)n * D_ * S_ + s0 + l;     // this thread's s-col
    short* x16b = x16 + (size_t)n * D_ * S_ + s0 + l;

    f32x4 acc[4];
#pragma unroll
    for (int st = 0; st < 4; ++st) acc[st] = (f32x4){0.f, 0.f, 0.f, 0.f};
    float ssl = 0.f;

    for (int dc = 0; dc < D_; dc += 64) {
        __syncthreads();
        // stage rows 2r,2r+1 for r = wv + 4t  (covers d-chunk rows 0..63)
#pragma unroll
        for (int t = 0; t < 8; ++t) {
            const int r = wv + 4 * t;
            float v0 = xb[(size_t)(dc + 2 * r) * S_];
            float v1 = xb[(size_t)(dc + 2 * r + 1) * S_];
            ssl += v0 * v0 + v1 * v1;
            unsigned lo = (unsigned short)f2bf(v0);
            unsigned hi = (unsigned short)f2bf(v1);
            unsigned p = lo | (hi << 16);
            ((unsigned*)T)[l * 34 + r] = p;                  // bank=(2l+r)%32: 4-way
            x16b[(size_t)(dc + 2 * r) * S_]     = (short)lo; // coalesced 128B store
            x16b[(size_t)(dc + 2 * r + 1) * S_] = (short)hi;
        }
        __syncthreads();

#pragma unroll
        for (int kst = 0; kst < 2; ++kst) {
            short8 af = *(const short8*)&w16[(16 * wv + lk) * D_ + dc + kst * 32 + q * 8];
#pragma unroll
            for (int st = 0; st < 4; ++st) {
                const short* bp = &T[(st * 16 + lk) * 68 + kst * 32 + q * 8];
                short4 b0 = *(const short4*)bp;
                short4 b1 = *(const short4*)(bp + 4);
                short8 bf = {b0.x, b0.y, b0.z, b0.w, b1.x, b1.y, b1.z, b1.w};
                acc[st] = __builtin_amdgcn_mfma_f32_16x16x32_bf16(af, bf, acc[st], 0, 0, 0);
            }
        }
    }

    // inv = 1/||x_s||: reduce ssl across the 4 waves (each covered 128 d per s)
    __syncthreads();
    pssq[wv][l] = ssl;
    __syncthreads();
    if (tid < 64) {
        float ss = pssq[0][tid] + pssq[1][tid] + pssq[2][tid] + pssq[3][tid];
        invL[tid] = 1.0f / fmaxf(sqrtf(ss), 1e-12f);
    }
    __syncthreads();

    // epilogue (identical to round-4 passing version)
    float lg[4][4], invv[4];
#pragma unroll
    for (int st = 0; st < 4; ++st) {
        invv[st] = invL[st * 16 + lk];
#pragma unroll
        for (int r = 0; r < 4; ++r) lg[st][r] = acc[st][r] * invv[st];
    }
    float mx[4];
#pragma unroll
    for (int st = 0; st < 4; ++st) {
        float m = fmaxf(fmaxf(lg[st][0], lg[st][1]), fmaxf(lg[st][2], lg[st][3]));
        m = fmaxf(m, __shfl_xor(m, 16));
        m = fmaxf(m, __shfl_xor(m, 32));
        mx[st] = m;
        if (q == 0) wred[0][wv][st * 16 + lk] = m;
    }
    __syncthreads();
    float gm[4];
#pragma unroll
    for (int st = 0; st < 4; ++st) {
        float m = wred[0][0][st * 16 + lk];
        m = fmaxf(m, wred[0][1][st * 16 + lk]);
        m = fmaxf(m, wred[0][2][st * 16 + lk]);
        m = fmaxf(m, wred[0][3][st * 16 + lk]);
        gm[st] = m;
    }
    float e[4][4];
#pragma unroll
    for (int st = 0; st < 4; ++st) {
        float s = 0.f;
#pragma unroll
        for (int r = 0; r < 4; ++r) {
            e[st][r] = __expf(lg[st][r] - gm[st]);
            s += e[st][r];
        }
        s += __shfl_xor(s, 16);
        s += __shfl_xor(s, 32);
        if (q == 0) wred[1][wv][st * 16 + lk] = s;
    }
    __syncthreads();
    float rs[4];
#pragma unroll
    for (int st = 0; st < 4; ++st) {
        float s = wred[1][0][st * 16 + lk] + wred[1][1][st * 16 + lk]
                + wred[1][2][st * 16 + lk] + wred[1][3][st * 16 + lk];
        rs[st] = 1.0f / s;
    }

    short* apb = aprime + (size_t)n * K_ * S_ + s0;
#pragma unroll
    for (int r = 0; r < 4; ++r) {
        const int k = 16 * wv + 4 * q + r;
        float accp = 0.f;
#pragma unroll
        for (int st = 0; st < 4; ++st) {
            float p = e[st][r] * rs[st];
            apb[(size_t)k * S_ + st * 16 + lk] = f2bf(p * invv[st]);
            accp += p;
        }
        accp += __shfl_xor(accp, 1);
        accp += __shfl_xor(accp, 2);
        accp += __shfl_xor(accp, 4);
        accp += __shfl_xor(accp, 8);
        if (lk == 0) atomicAdd(&asum[n * K_ + k], accp);
    }
}

// ---------------------------------------------------------------------------
// kB: LDS-free MFMA GEMM. agg[k][d] partial over s-split:
//   agg[k][d] = sum_s aprime[k][s] * x16[d][s]   (both bf16, s-contiguous)
// grid: n(32) x dtile(4 of 128) x split(10 of 160s) = 1280 blocks x 256 thr.
// 5 K-steps fully unrolled -> deep load hoisting; 10 partial buffers.
// ---------------------------------------------------------------------------
__global__ __launch_bounds__(256) void kB(const short* __restrict__ x16,
                                          const short* __restrict__ aprime,
                                          float* __restrict__ aggp)
{
    const int bid = blockIdx.x;
    const int n  = bid / 40;
    const int dt = (bid % 40) / 10;
    const int sp = bid % 10;
    const int wv = threadIdx.x >> 6;
    const int l  = threadIdx.x & 63;
    const int lk = l & 15;
    const int q  = l >> 4;
    const int dbase = dt * 128 + wv * 32;

    const short* ap = aprime + (size_t)n * K_ * S_;
    const short* xb = x16 + (size_t)n * D_ * S_;

    f32x4 acc[4][2];
#pragma unroll
    for (int kt = 0; kt < 4; ++kt)
#pragma unroll
        for (int ds = 0; ds < 2; ++ds) acc[kt][ds] = (f32x4){0.f, 0.f, 0.f, 0.f};

#pragma unroll
    for (int kst = 0; kst < 5; ++kst) {
        const int s = sp * 160 + kst * 32 + q * 8;
        short8 af[4];
#pragma unroll
        for (int kt = 0; kt < 4; ++kt)
            af[kt] = *(const short8*)&ap[(size_t)(kt * 16 + lk) * S_ + s];
        short8 bf[2];
#pragma unroll
        for (int ds = 0; ds < 2; ++ds)
            bf[ds] = *(const short8*)&xb[(size_t)(dbase + ds * 16 + lk) * S_ + s];
#pragma unroll
        for (int kt = 0; kt < 4; ++kt)
#pragma unroll
            for (int ds = 0; ds < 2; ++ds)
                acc[kt][ds] = __builtin_amdgcn_mfma_f32_16x16x32_bf16(af[kt], bf[ds], acc[kt][ds], 0, 0, 0);
    }

    float* ab = aggp + ((size_t)sp * N_ + n) * K_ * D_;
#pragma unroll
    for (int kt = 0; kt < 4; ++kt)
#pragma unroll
        for (int ds = 0; ds < 2; ++ds)
#pragma unroll
            for (int r = 0; r < 4; ++r)
                ab[(size_t)(kt * 16 + 4 * q + r) * D_ + dbase + ds * 16 + lk] = acc[kt][ds][r];
}

// ---------------------------------------------------------------------------
// kC: vlad = (sum of 10 agg partials) - asum*centroid; intra-L2-norm over d;
// global norm = /sqrt(K) = /8 exactly. grid: 2048 blocks x 256 thr.
// ---------------------------------------------------------------------------
__global__ __launch_bounds__(256) void kC(const float* __restrict__ aggp,
                                          const float* __restrict__ asum,
                                          const float* __restrict__ cent,
                                          float* __restrict__ out)
{
    __shared__ float red[4];
    const int tid = threadIdx.x;
    const int nk = blockIdx.x;
    const int k = nk & 63;
    const float as = asum[nk];
    const float* cb = cent + (size_t)k * D_;

    float v0 = 0.f, v1 = 0.f;
#pragma unroll
    for (int p = 0; p < 10; ++p) {
        const float* ag = aggp + (size_t)p * N_ * K_ * D_ + (size_t)nk * D_;
        v0 += ag[tid];
        v1 += ag[tid + 256];
    }
    v0 -= as * cb[tid];
    v1 -= as * cb[tid + 256];
    float ssq = v0 * v0 + v1 * v1;

    ssq += __shfl_xor(ssq, 32);
    ssq += __shfl_xor(ssq, 16);
    ssq += __shfl_xor(ssq, 8);
    ssq += __shfl_xor(ssq, 4);
    ssq += __shfl_xor(ssq, 2);
    ssq += __shfl_xor(ssq, 1);
    if ((tid & 63) == 0) red[tid >> 6] = ssq;
    __syncthreads();
    const float total = red[0] + red[1] + red[2] + red[3];
    const float scale = 1.0f / (fmaxf(sqrtf(total), 1e-12f) * 8.0f);

    out[(size_t)nk * D_ + tid]       = v0 * scale;
    out[(size_t)nk * D_ + tid + 256] = v1 * scale;
}

// ---------------------------------------------------------------------------
extern "C" void kernel_launch(void* const* d_in, const int* in_sizes, int n_in,
                              void* d_out, int out_size, void* d_ws, size_t ws_size,
                              hipStream_t stream)
{
    const float* x    = (const float*)d_in[0];   // [32,512,40,40]
    const float* w    = (const float*)d_in[1];   // [64,512]
    const float* cent = (const float*)d_in[2];   // [64,512]
    float* out = (float*)d_out;                  // [32, 32768]

    // ws carve (~97 MB), fp32 first, all 16B-aligned
    float* aggp   = (float*)d_ws;                          // 10*N*K*D fp32
    float* asum   = aggp + (size_t)10 * N_ * K_ * D_;      // N*K fp32
    short* aprime = (short*)(asum + N_ * K_);              // N*K*S bf16
    short* w16    = aprime + (size_t)N_ * K_ * S_;         // K*D bf16
    short* x16    = w16 + (size_t)K_ * D_;                 // N*D*S bf16

    hipMemsetAsync(asum, 0, (size_t)N_ * K_ * sizeof(float), stream);

    kW<<<32, 256, 0, stream>>>(w, w16);
    kA<<<N_ * (S_ / 64), 256, 0, stream>>>(x, w16, x16, aprime, asum);
    kB<<<N_ * 4 * 10, 256, 0, stream>>>(x16, aprime, aggp);
    kC<<<N_ * K_, 256, 0, stream>>>(aggp, asum, cent, out);
}